// Round 5
// baseline (32.102 us; speedup 1.0000x reference)
//
#include <hip/hip_runtime.h>
#include <math.h>

#define BN 1024
#define CN 10
#define DN 16
#define NP2 136     // sorted pairs (i<=j)
#define NE1 16
#define NE2 136
#define NE3 816
#define NE4 3876
#define NENT 4844   // 16+136+816+3876 sorted tuples
#define EB 19       // ceil(4844/256) entry-blocks per cluster
#define CH 88       // member chunk (Q fits 64KB static LDS)
#define SST 92      // LDS row stride floats: %4==0 (float4 rows), 23 mod 8 = 7 -> spread
#define EPSV 1e-7f

__device__ __forceinline__ int H2f(int n){ return n*(n+1)/2; }
__device__ __forceinline__ int H3f(int n){ return n*(n+1)*(n+2)/6; }
__device__ __forceinline__ int rank2(int i,int j){ return i*DN - (i*(i-1))/2 + (j-i); }

// signed compressive roots (match reference params exactly)
__device__ __forceinline__ float sroot2f(float x){
  float s = (x<0.f)?-1.f:1.f;
  return s*(sqrtf(fabsf(x)+0.25f)-0.5f);
}
__device__ __forceinline__ float sroot3f(float x){
  float s=(x<0.f)?-1.f:1.f;
  return s*(cbrtf(fabsf(x)+0.19245008973f)-0.57735026919f);
}
__device__ __forceinline__ float sroot4f(float x){
  float s=(x<0.f)?-1.f:1.f;
  return s*(sqrtf(sqrtf(fabsf(x)+0.15749013123f))-0.62996052494f);
}

// Single fused kernel: block = (cluster c, entry-chunk eb). Redundant per-block
// argmax assignment (float2 logit loads) + ballot compaction; per-thread tuple
// unranking; per chunk: stage member diffs sx[16][.], cooperatively build the
// pair-product matrix Q[136][.] (Q[p]=v_i*v_j), then orders 2/3/4 read 1/2/2
// LDS rows instead of 2/3/4 -> ~2x fewer b128 reads in the dominant phase.
// Wave-shuffle reduce; atomicAdd into out[0] (memset to 0 before launch).
__global__ __launch_bounds__(256) void kb(
    const float* __restrict__ emb, const float* __restrict__ centers,
    const float* __restrict__ logits,
    const float* __restrict__ gm1, const float* __restrict__ gm2,
    const float* __restrict__ gm3, const float* __restrict__ gm4,
    float* __restrict__ out) {
  __shared__ float sx[DN][SST];     // member diffs, component-major
  __shared__ float Q[NP2][SST];     // pair products
  __shared__ int   memb[BN];
  __shared__ int   wcnt[4][4];      // [round][wave]
  __shared__ float wred[4];
  int tid  = threadIdx.x;
  int lane = tid & 63;
  int wave = tid >> 6;              // 4 waves
  int c  = blockIdx.x / EB;
  int eb = blockIdx.x % EB;

  // --- assignment ballots (samples ascending; float2 loads: rows are 40B -> 8B aligned) ---
  int rank_r[4]; bool match_r[4];
  #pragma unroll
  for (int r=0;r<4;r++) {
    int b = r*256 + tid;
    const float2* l2 = (const float2*)(logits + b*CN);
    float2 q0=l2[0], q1=l2[1], q2=l2[2], q3=l2[3], q4=l2[4];
    float vv[10] = {q0.x,q0.y,q1.x,q1.y,q2.x,q2.y,q3.x,q3.y,q4.x,q4.y};
    float best = vv[0]; int bi = 0;
    #pragma unroll
    for (int q=1;q<CN;q++){ if (vv[q]>best){best=vv[q];bi=q;} }  // first-max like jnp.argmax
    unsigned long long m = __ballot(bi==c);
    match_r[r] = (bi==c);
    rank_r[r] = __popcll(m & ((1ull<<lane)-1ull));
    if (lane==0) wcnt[r][wave] = __popcll(m);
  }

  // --- unrank entry e -> sorted tuple (ii<=jj<=kk<=ll), order, target, pair ranks ---
  int e = eb*256 + tid;
  int ii=0, jj=0, kk=0, ll=0, order=0;
  float tg = 0.f;
  bool valid = (e < NENT);
  if (valid) {
    if (e < NE1) {
      order=1; ii=e;
      tg = gm1[ii];                               // no sroot for order 1
    } else if (e < NE1+NE2) {
      order=2; int r = e-NE1;
      int i=0; while (r >= DN-i){ r -= DN-i; i++; }
      ii=i; jj=i+r;
      tg = sroot2f(gm2[ii*DN+jj]);
    } else if (e < NE1+NE2+NE3) {
      order=3; int r = e-(NE1+NE2);
      int i=0; while (r >= H2f(DN-i)){ r -= H2f(DN-i); i++; }
      int j=i; while (r >= DN-j){ r -= DN-j; j++; }
      ii=i; jj=j; kk=j+r;
      tg = sroot3f(gm3[(ii*DN+jj)*DN+kk]);
    } else {
      order=4; int r = e-(NE1+NE2+NE3);
      int i=0; while (r >= H3f(DN-i)){ r -= H3f(DN-i); i++; }
      int j=i; while (r >= H2f(DN-j)){ r -= H2f(DN-j); j++; }
      int k=j; while (r >= DN-k){ r -= DN-k; k++; }
      ii=i; jj=j; kk=k; ll=k+r;
      tg = sroot4f(gm4[((ii*DN+jj)*DN+kk)*DN+ll]);
    }
  }

  // row pointers: order1: sum sx[ii]; order2: sum Q[r2(ii,jj)];
  // order3: dot(Q[r2(ii,jj)], sx[kk]); order4: dot(Q[r2(ii,jj)], Q[r2(kk,ll)])
  const float* PA = &sx[0][0];
  const float* PB = &sx[0][0];
  if (order==1)      PA = &sx[ii][0];
  else if (order==2) PA = &Q[rank2(ii,jj)][0];
  else if (order==3) { PA = &Q[rank2(ii,jj)][0]; PB = &sx[kk][0]; }
  else if (order==4) { PA = &Q[rank2(ii,jj)][0]; PB = &Q[rank2(kk,ll)][0]; }

  __syncthreads();
  int pre[17]; pre[0]=0;
  #pragma unroll
  for (int p=0;p<16;p++) pre[p+1] = pre[p] + wcnt[p>>2][p&3];
  int cnt = pre[16];
  #pragma unroll
  for (int r=0;r<4;r++)
    if (match_r[r]) memb[pre[r*4+wave] + rank_r[r]] = r*256 + tid;

  // Q-build pair range for this wave: p in [34*wave, 34*wave+34)
  int qp0 = 34*wave;
  int qi=0, qrem=qp0; while (qrem >= DN-qi){ qrem -= DN-qi; qi++; }
  int qj0 = qi + qrem;

  float mom = 0.f;
  for (int base=0; base<cnt; base+=CH) {
    int m  = min(CH, cnt-base);
    int mp = (m+3)&~3;            // pad to float4 multiple
    __syncthreads();              // protects memb (1st iter) / previous chunk
    if (tid < m) {
      int b = memb[base + tid];
      const float4* er = (const float4*)(emb + b*DN);
      const float4* cr = (const float4*)(centers + c*DN);
      float4 e0=er[0], e1=er[1], e2=er[2], e3=er[3];
      float4 c0=cr[0], c1=cr[1], c2=cr[2], c3=cr[3];
      float v[16];
      v[0]=e0.x-c0.x; v[1]=e0.y-c0.y; v[2]=e0.z-c0.z; v[3]=e0.w-c0.w;
      v[4]=e1.x-c1.x; v[5]=e1.y-c1.y; v[6]=e1.z-c1.z; v[7]=e1.w-c1.w;
      v[8]=e2.x-c2.x; v[9]=e2.y-c2.y; v[10]=e2.z-c2.z; v[11]=e2.w-c2.w;
      v[12]=e3.x-c3.x; v[13]=e3.y-c3.y; v[14]=e3.z-c3.z; v[15]=e3.w-c3.w;
      #pragma unroll
      for (int i=0;i<DN;i++) sx[i][tid] = v[i];
    }
    if (tid < DN)                 // zero the float4 padding tail
      for (int n=m; n<mp; n++) sx[tid][n] = 0.f;
    __syncthreads();
    // --- build Q for this chunk: wave w covers pairs [34w,34w+34), all columns ---
    for (int n0=lane; n0<mp; n0+=64) {
      float v[DN];
      #pragma unroll
      for (int i=0;i<DN;i++) v[i] = sx[i][n0];
      int pi=qi, pj=qj0;
      #pragma unroll
      for (int t=0;t<34;t++) {
        Q[qp0+t][n0] = v[pi]*v[pj];
        pj++; if (pj==DN){ pi++; pj=pi; }
      }
    }
    __syncthreads();
    // --- accumulate ---
    if (order>=3) {               // dot of two rows
      for (int n=0; n<mp; n+=4) {
        float4 a=*(const float4*)(PA+n), b=*(const float4*)(PB+n);
        mom += a.x*b.x + a.y*b.y + a.z*b.z + a.w*b.w;
      }
    } else if (order>=1) {        // plain sum of one row
      for (int n=0; n<mp; n+=4) {
        float4 a=*(const float4*)(PA+n);
        mom += a.x + a.y + a.z + a.w;
      }
    }
  }

  float contrib = 0.f;
  if (valid) {
    float mval = mom;
    if (order <= 2) mval /= ((float)cnt + EPSV);
    float v;
    if      (order==1) v = mval - tg;
    else if (order==2) v = sroot2f(mval) - tg;
    else if (order==3) v = sroot3f(mval) - tg;
    else               v = sroot4f(mval) - tg;
    float lw = (order==1)?1.f:(order==2)?0.5f:(order==3)?0.25f:0.125f;
    float cwn = (float)cnt * (1.f/1024.f);   // sum(cw) == B exactly
    contrib = lw * cwn * v * v;
  }

  // wave shuffle reduce (no syncs), then one atomic per block
  #pragma unroll
  for (int off=32; off; off>>=1) contrib += __shfl_down(contrib, off, 64);
  if (lane==0) wred[wave] = contrib;
  __syncthreads();
  if (tid==0) atomicAdd(out, wred[0]+wred[1]+wred[2]+wred[3]);
}

extern "C" void kernel_launch(void* const* d_in, const int* in_sizes, int n_in,
                              void* d_out, int out_size, void* d_ws, size_t ws_size,
                              hipStream_t stream) {
  const float* emb  = (const float*)d_in[0];   // [1024,16]
  const float* cen  = (const float*)d_in[1];   // [10,16]
  const float* logi = (const float*)d_in[2];   // [1024,10]
  const float* gm1  = (const float*)d_in[3];   // [16]
  const float* gm2  = (const float*)d_in[4];   // [16,16]
  const float* gm3  = (const float*)d_in[5];   // [16^3]
  const float* gm4  = (const float*)d_in[6];   // [16^4]
  // mw1..mw4 (d_in[7..10]) unused: mw[tuple] * #perms(tuple) == 1 exactly.

  hipMemsetAsync(d_out, 0, sizeof(float), stream);   // graph-capturable memset node
  kb<<<CN*EB, 256, 0, stream>>>(emb, cen, logi, gm1, gm2, gm3, gm4, (float*)d_out);
}

// Round 6
// 18.133 us; speedup vs baseline: 1.7704x; 1.7704x over previous
//
#include <hip/hip_runtime.h>
#include <math.h>

#define BN 1024
#define CN 10
#define DN 16
#define NE1 16
#define NE2 136
#define NE3 816
#define NE4 3876
#define NENT 4844   // 16+136+816+3876 sorted tuples
#define EB 19       // ceil(4844/256) entry-blocks per cluster
#define CH 256      // member chunk staged in LDS
#define SST 260     // LDS row stride (floats): %4==0 for float4; 260 mod 32 = 4 -> rows pair only 2-way (free)
#define EPSV 1e-7f

__device__ __forceinline__ int H2f(int n){ return n*(n+1)/2; }
__device__ __forceinline__ int H3f(int n){ return n*(n+1)*(n+2)/6; }

// signed compressive roots (match reference params exactly)
__device__ __forceinline__ float sroot2f(float x){
  float s = (x<0.f)?-1.f:1.f;
  return s*(sqrtf(fabsf(x)+0.25f)-0.5f);
}
__device__ __forceinline__ float sroot3f(float x){
  float s=(x<0.f)?-1.f:1.f;
  return s*(cbrtf(fabsf(x)+0.19245008973f)-0.57735026919f);
}
__device__ __forceinline__ float sroot4f(float x){
  float s=(x<0.f)?-1.f:1.f;
  return s*(sqrtf(sqrtf(fabsf(x)+0.15749013123f))-0.62996052494f);
}

// Single fused kernel (R4 structure): block = (cluster c, entry-chunk eb).
// Redundant per-block argmax assignment (float2 logit loads) + ballot
// compaction into LDS; per-thread tuple unranking; member diffs staged in a
// component-major LDS tile (stride 260 -> float4 rows, 2-way-max bank
// aliasing = free); per-order float4 inner loops; wave-shuffle reduce;
// atomicAdd into out[0] (memset to 0 on stream before launch).
__global__ __launch_bounds__(256) void kb(
    const float* __restrict__ emb, const float* __restrict__ centers,
    const float* __restrict__ logits,
    const float* __restrict__ gm1, const float* __restrict__ gm2,
    const float* __restrict__ gm3, const float* __restrict__ gm4,
    float* __restrict__ out) {
  __shared__ float sx[DN][SST];
  __shared__ int   memb[BN];
  __shared__ int   wcnt[4][4];   // [round][wave]
  __shared__ float wred[4];
  int tid  = threadIdx.x;
  int lane = tid & 63;
  int wave = tid >> 6;           // 4 waves
  int c  = blockIdx.x / EB;
  int eb = blockIdx.x % EB;

  // --- assignment ballots (samples ascending; rows are 40B -> float2-aligned) ---
  int rank_r[4]; bool match_r[4];
  #pragma unroll
  for (int r=0;r<4;r++) {
    int b = r*256 + tid;
    const float2* l2 = (const float2*)(logits + b*CN);
    float2 q0=l2[0], q1=l2[1], q2=l2[2], q3=l2[3], q4=l2[4];
    float vv[10] = {q0.x,q0.y,q1.x,q1.y,q2.x,q2.y,q3.x,q3.y,q4.x,q4.y};
    float best = vv[0]; int bi = 0;
    #pragma unroll
    for (int q=1;q<CN;q++){ if (vv[q]>best){best=vv[q];bi=q;} }  // first-max like jnp.argmax
    unsigned long long m = __ballot(bi==c);
    match_r[r] = (bi==c);
    rank_r[r] = __popcll(m & ((1ull<<lane)-1ull));
    if (lane==0) wcnt[r][wave] = __popcll(m);
  }

  // --- unrank entry e -> sorted tuple (ii<=jj<=kk<=ll), order, target ---
  // (before the sync so the scattered gm load latency overlaps)
  int e = eb*256 + tid;
  int ii=0, jj=0, kk=0, ll=0, order=0;
  float tg = 0.f;
  bool valid = (e < NENT);
  if (valid) {
    if (e < NE1) {
      order=1; ii=e;
      tg = gm1[ii];                               // no sroot for order 1
    } else if (e < NE1+NE2) {
      order=2; int r = e-NE1;
      int i=0; while (r >= DN-i){ r -= DN-i; i++; }
      ii=i; jj=i+r;
      tg = sroot2f(gm2[ii*DN+jj]);
    } else if (e < NE1+NE2+NE3) {
      order=3; int r = e-(NE1+NE2);
      int i=0; while (r >= H2f(DN-i)){ r -= H2f(DN-i); i++; }
      int j=i; while (r >= DN-j){ r -= DN-j; j++; }
      ii=i; jj=j; kk=j+r;
      tg = sroot3f(gm3[(ii*DN+jj)*DN+kk]);
    } else {
      order=4; int r = e-(NE1+NE2+NE3);
      int i=0; while (r >= H3f(DN-i)){ r -= H3f(DN-i); i++; }
      int j=i; while (r >= H2f(DN-j)){ r -= H2f(DN-j); j++; }
      int k=j; while (r >= DN-k){ r -= DN-k; k++; }
      ii=i; jj=j; kk=k; ll=k+r;
      tg = sroot4f(gm4[((ii*DN+jj)*DN+kk)*DN+ll]);
    }
  }

  __syncthreads();
  int pre[17]; pre[0]=0;
  #pragma unroll
  for (int p=0;p<16;p++) pre[p+1] = pre[p] + wcnt[p>>2][p&3];
  int cnt = pre[16];
  #pragma unroll
  for (int r=0;r<4;r++)
    if (match_r[r]) memb[pre[r*4+wave] + rank_r[r]] = r*256 + tid;

  const float* pA = &sx[ii][0];
  const float* pB = &sx[jj][0];
  const float* pC = &sx[kk][0];
  const float* pD = &sx[ll][0];

  // loop-invariant center row (c fixed per block)
  const float4* cr = (const float4*)(centers + c*DN);
  float4 c0=cr[0], c1=cr[1], c2=cr[2], c3=cr[3];

  float mom = 0.f;
  for (int base=0; base<cnt; base+=CH) {   // runs once for cnt<=256 (always here)
    int m  = min(CH, cnt-base);
    int mp = (m+3)&~3;            // pad to float4 multiple
    __syncthreads();              // protects memb (1st iter) / previous chunk
    if (tid < m) {
      int b = memb[base + tid];
      const float4* er = (const float4*)(emb + b*DN);
      float4 e0=er[0], e1=er[1], e2=er[2], e3=er[3];
      float v[16];
      v[0]=e0.x-c0.x; v[1]=e0.y-c0.y; v[2]=e0.z-c0.z; v[3]=e0.w-c0.w;
      v[4]=e1.x-c1.x; v[5]=e1.y-c1.y; v[6]=e1.z-c1.z; v[7]=e1.w-c1.w;
      v[8]=e2.x-c2.x; v[9]=e2.y-c2.y; v[10]=e2.z-c2.z; v[11]=e2.w-c2.w;
      v[12]=e3.x-c3.x; v[13]=e3.y-c3.y; v[14]=e3.z-c3.z; v[15]=e3.w-c3.w;
      #pragma unroll
      for (int i=0;i<DN;i++) sx[i][tid] = v[i];
    }
    if (tid < DN)                 // zero the float4 padding tail
      for (int n=m; n<mp; n++) sx[tid][n] = 0.f;
    __syncthreads();
    if (order==4) {
      for (int n=0; n<mp; n+=4) {
        float4 a=*(const float4*)(pA+n), b=*(const float4*)(pB+n);
        float4 cc=*(const float4*)(pC+n), d=*(const float4*)(pD+n);
        mom += a.x*b.x*cc.x*d.x + a.y*b.y*cc.y*d.y
             + a.z*b.z*cc.z*d.z + a.w*b.w*cc.w*d.w;
      }
    } else if (order==3) {
      for (int n=0; n<mp; n+=4) {
        float4 a=*(const float4*)(pA+n), b=*(const float4*)(pB+n);
        float4 cc=*(const float4*)(pC+n);
        mom += a.x*b.x*cc.x + a.y*b.y*cc.y + a.z*b.z*cc.z + a.w*b.w*cc.w;
      }
    } else if (order==2) {
      for (int n=0; n<mp; n+=4) {
        float4 a=*(const float4*)(pA+n), b=*(const float4*)(pB+n);
        mom += a.x*b.x + a.y*b.y + a.z*b.z + a.w*b.w;
      }
    } else if (order==1) {
      for (int n=0; n<mp; n+=4) {
        float4 a=*(const float4*)(pA+n);
        mom += a.x + a.y + a.z + a.w;
      }
    }
  }

  float contrib = 0.f;
  if (valid) {
    float mval = mom;
    if (order <= 2) mval /= ((float)cnt + EPSV);
    float v;
    if      (order==1) v = mval - tg;
    else if (order==2) v = sroot2f(mval) - tg;
    else if (order==3) v = sroot3f(mval) - tg;
    else               v = sroot4f(mval) - tg;
    float lw = (order==1)?1.f:(order==2)?0.5f:(order==3)?0.25f:0.125f;
    float cwn = (float)cnt * (1.f/1024.f);   // sum(cw) == B exactly
    contrib = lw * cwn * v * v;
  }

  // wave shuffle reduce (no syncs), then one atomic per block
  #pragma unroll
  for (int off=32; off; off>>=1) contrib += __shfl_down(contrib, off, 64);
  if (lane==0) wred[wave] = contrib;
  __syncthreads();
  if (tid==0) atomicAdd(out, wred[0]+wred[1]+wred[2]+wred[3]);
}

extern "C" void kernel_launch(void* const* d_in, const int* in_sizes, int n_in,
                              void* d_out, int out_size, void* d_ws, size_t ws_size,
                              hipStream_t stream) {
  const float* emb  = (const float*)d_in[0];   // [1024,16]
  const float* cen  = (const float*)d_in[1];   // [10,16]
  const float* logi = (const float*)d_in[2];   // [1024,10]
  const float* gm1  = (const float*)d_in[3];   // [16]
  const float* gm2  = (const float*)d_in[4];   // [16,16]
  const float* gm3  = (const float*)d_in[5];   // [16^3]
  const float* gm4  = (const float*)d_in[6];   // [16^4]
  // mw1..mw4 (d_in[7..10]) unused: mw[tuple] * #perms(tuple) == 1 exactly.

  hipMemsetAsync(d_out, 0, sizeof(float), stream);   // graph-capturable memset node
  kb<<<CN*EB, 256, 0, stream>>>(emb, cen, logi, gm1, gm2, gm3, gm4, (float*)d_out);
}